// Round 14
// baseline (43.590 us; speedup 1.0000x reference)
//
#include <hip/hip_runtime.h>
#include <hip/hip_bf16.h>

typedef __attribute__((ext_vector_type(8))) short short8;
typedef __attribute__((ext_vector_type(4))) short short4v;
typedef __attribute__((ext_vector_type(4))) float floatx4;
typedef __attribute__((ext_vector_type(4))) unsigned int uintx4;
typedef __attribute__((ext_vector_type(4))) int intx4;
typedef unsigned int u32;
typedef unsigned short u16;

#define NB 1024
#define ND 16
#define NM 4
#define NR 4096
#define NC 64
#define EPSF 1e-9f
#define KSPLIT 32

__device__ inline u16 f2bf(float f) {
    u32 u;
    __builtin_memcpy(&u, &f, 4);
    u32 lsb = (u >> 16) & 1;
    u += 0x7fffu + lsb;   // round-to-nearest-even
    return (u16)(u >> 16);
}

// ---- probe: empty kernel to measure per-graph-node replay overhead ----
__global__ void k_nop() {}

// ---- Kernel 1 (tiny): pack rules -> 2 bits x 16 dims per u32 ----
__global__ __launch_bounds__(256) void k_pack(const int* __restrict__ rules,
                                              u32* __restrict__ packed) {
    int r = blockIdx.x * 256 + threadIdx.x;
    const int* q = rules + (size_t)r * ND;
    u32 pk = 0;
#pragma unroll
    for (int i = 0; i < 4; ++i) {
        intx4 v = *(const intx4*)(q + i * 4);
#pragma unroll
        for (int e = 0; e < 4; ++e) pk |= ((u32)(v[e] & 3)) << (2 * (i * 4 + e));
    }
    packed[r] = pk;
}

// ---- Kernel 2 (fused): blocks 0..255 = cons-reduce; blocks 256..1279 = per-b fs ----
__global__ __launch_bounds__(256) void k_mid(const float* __restrict__ cons,
                                             const float* __restrict__ x,
                                             const float* __restrict__ centers,
                                             const float* __restrict__ widths,
                                             const u32* __restrict__ packed,
                                             u16* __restrict__ s_consT,
                                             float* __restrict__ out_nfs,
                                             u16* __restrict__ fs_bf,
                                             float* __restrict__ out_xe,
                                             float* __restrict__ rowscale) {
    __shared__ u16 tile[16][68];
    __shared__ float xv[16];
    __shared__ float mftab[64];
    __shared__ float gtab[1024];
    __shared__ float wred[4];
    __shared__ float s_inv;
    int bid = blockIdx.x;
    int tid = threadIdx.x;
    if (bid < 256) {
        int rbase = bid * 16;
        int c = tid & 63;
        int rr = tid >> 6;
#pragma unroll
        for (int it = 0; it < 4; ++it, rr += 4) {
            const float* p = cons + (size_t)(rbase + rr) * (ND + 1) * NC + c;
            float s = 0.f;
#pragma unroll
            for (int j = 0; j < ND + 1; ++j) s += p[j * NC];
            tile[rr][c] = f2bf(s);
        }
        __syncthreads();
        int cc = tid >> 2;
        int r0 = (tid & 3) * 4;
        short4v v;
#pragma unroll
        for (int e = 0; e < 4; ++e) v[e] = (short)tile[r0 + e][cc];
        *(short4v*)(s_consT + (size_t)cc * NR + rbase + r0) = v;
        return;
    }
    int b = bid - 256;
    if (tid < 16) {
        float raw = x[b * 16 + tid];
        xv[tid] = raw;
        out_xe[b * 17 + tid] = raw;
    }
    if (tid == 16) out_xe[b * 17 + 16] = 1.0f;
    __syncthreads();
    if (tid < 64) {
        float diff = xv[tid >> 2] - centers[tid];
        float w = widths[tid];
        mftab[tid] = __expf(-diff * diff / (2.f * w * w)) + EPSF;
    }
    __syncthreads();
    for (int idx = tid; idx < 1024; idx += 256) {
        int g = idx >> 8, i = idx & 255;
        const float* mf = mftab + g * 16;
        gtab[idx] = mf[0 + (i & 3)] * mf[4 + ((i >> 2) & 3)] *
                    mf[8 + ((i >> 4) & 3)] * mf[12 + ((i >> 6) & 3)];
    }
    __syncthreads();
    floatx4 f[4];
    float lsum = 0.f;
#pragma unroll
    for (int it = 0; it < 4; ++it) {
        int r = it * 1024 + tid * 4;
        uintx4 p = *(const uintx4*)(packed + r);
#pragma unroll
        for (int e = 0; e < 4; ++e) {
            u32 pk = p[e];
            f[it][e] = gtab[pk & 255] * gtab[256 + ((pk >> 8) & 255)] *
                       gtab[512 + ((pk >> 16) & 255)] * gtab[768 + (pk >> 24)];
            lsum += f[it][e];
        }
    }
    for (int off = 32; off; off >>= 1) lsum += __shfl_down(lsum, off, 64);
    if ((tid & 63) == 0) wred[tid >> 6] = lsum;
    __syncthreads();
    if (tid == 0) s_inv = 1.f / (wred[0] + wred[1] + wred[2] + wred[3] + EPSF);
    __syncthreads();
    float inv = s_inv;
    if (tid == 0) {
        float s = 1.f;
        for (int i = 0; i < 16; ++i) s += xv[i];
        rowscale[b] = s * inv;
    }
    float* on = out_nfs + (size_t)b * NR;
    u16* ob = fs_bf + (size_t)b * NR;
#pragma unroll
    for (int it = 0; it < 4; ++it) {
        int r = it * 1024 + tid * 4;
        floatx4 v;
        short4v bv;
#pragma unroll
        for (int e = 0; e < 4; ++e) {
            v[e] = f[it][e] * inv;
            bv[e] = (short)f2bf(f[it][e]);
        }
        *(floatx4*)(on + r) = v;
        *(short4v*)(ob + r) = bv;
    }
}

// ---- Kernel 3: bf16 fs (B x R) @ s_cons (R x C), KSPLIT=32, bf16 partials ----
__global__ __launch_bounds__(256) void k_gemm(const u16* __restrict__ fs_bf,
                                              const u16* __restrict__ s_consT,
                                              u16* __restrict__ part) {
    int rt = blockIdx.x;
    int ks = blockIdx.y;
    int tid = threadIdx.x;
    int wid = tid >> 6, lane = tid & 63;
    int arow = rt * 64 + wid * 16 + (lane & 15);
    int kbase = ks * (NR / KSPLIT) + (lane >> 4) * 8;
    const u16* aptr = fs_bf + (size_t)arow * NR + kbase;
    const u16* bptr = s_consT + (size_t)(lane & 15) * NR + kbase;
    floatx4 acc[4] = {};
#pragma unroll
    for (int t = 0; t < (NR / KSPLIT) / 32; ++t) {
        short8 af = *(const short8*)(aptr + t * 32);
#pragma unroll
        for (int cb = 0; cb < 4; ++cb) {
            short8 bf = *(const short8*)(bptr + (size_t)cb * 16 * NR + t * 32);
            acc[cb] = __builtin_amdgcn_mfma_f32_16x16x32_bf16(af, bf, acc[cb], 0, 0, 0);
        }
    }
    u16* po = part + (size_t)ks * (NB * NC);
    int row0 = rt * 64 + wid * 16 + (lane >> 4) * 4;
#pragma unroll
    for (int cb = 0; cb < 4; ++cb)
#pragma unroll
        for (int reg = 0; reg < 4; ++reg)
            po[(size_t)(row0 + reg) * NC + cb * 16 + (lane & 15)] = f2bf(acc[cb][reg]);
}

// ---- Kernel 4: reduce K-splits, scale by rowscale = sx/den ----
__global__ __launch_bounds__(256) void k_out(const u16* __restrict__ part,
                                             const float* __restrict__ rowscale,
                                             float* __restrict__ out0) {
    int t = blockIdx.x * 256 + threadIdx.x;
    float a = 0.f;
#pragma unroll
    for (int ks = 0; ks < KSPLIT; ++ks) {
        u32 u = ((u32)part[(size_t)ks * (NB * NC) + t]) << 16;
        float v;
        __builtin_memcpy(&v, &u, 4);
        a += v;
    }
    out0[t] = a * rowscale[t >> 6];
}

extern "C" void kernel_launch(void* const* d_in, const int* in_sizes, int n_in,
                              void* d_out, int out_size, void* d_ws, size_t ws_size,
                              hipStream_t stream) {
    const float* x = (const float*)d_in[0];
    const float* centers = (const float*)d_in[1];
    const float* widths = (const float*)d_in[2];
    const float* cons = (const float*)d_in[3];
    const int* rules = (const int*)d_in[4];

    float* out = (float*)d_out;
    float* out_rule = out;                        // [1024,64]
    float* out_nfs = out + NB * NC;               // [1024,4096]
    float* out_xe = out + NB * NC + NB * NR;      // [1024,17]

    char* ws = (char*)d_ws;
    u16* s_consT = (u16*)ws;                                   // 512 KB
    u32* packed = (u32*)(ws + (512 << 10));                    // 16 KB
    float* rowscale = (float*)(ws + (512 << 10) + (16 << 10)); // 4 KB
    u16* fs_bf = (u16*)(ws + (512 << 10) + (24 << 10));        // 8 MB
    u16* part = (u16*)(ws + (512 << 10) + (24 << 10) + (size_t)NB * NR * 2);  // 4 MB

    k_pack<<<NR / 256, 256, 0, stream>>>(rules, packed);
    k_mid<<<256 + NB, 256, 0, stream>>>(cons, x, centers, widths, packed,
                                        s_consT, out_nfs, fs_bf, out_xe, rowscale);
    k_gemm<<<dim3(16, KSPLIT), 256, 0, stream>>>(fs_bf, s_consT, part);
    k_out<<<(NB * NC) / 256, 256, 0, stream>>>(part, rowscale, out_rule);
    // ---- 8-node nop chain: measures per-node graph replay overhead o ----
    // total = 31.6 + 8*o  (o>=1us -> clearly visible)
#pragma unroll
    for (int i = 0; i < 8; ++i) k_nop<<<1, 64, 0, stream>>>();
}

// Round 15
// 31.714 us; speedup vs baseline: 1.3745x; 1.3745x over previous
//
#include <hip/hip_runtime.h>
#include <hip/hip_bf16.h>

typedef __attribute__((ext_vector_type(8))) short short8;
typedef __attribute__((ext_vector_type(4))) short short4v;
typedef __attribute__((ext_vector_type(4))) float floatx4;
typedef __attribute__((ext_vector_type(4))) unsigned int uintx4;
typedef __attribute__((ext_vector_type(4))) int intx4;
typedef unsigned int u32;
typedef unsigned short u16;

#define NB 1024
#define ND 16
#define NM 4
#define NR 4096
#define NC 64
#define EPSF 1e-9f
#define KSPLIT 32

__device__ inline u16 f2bf(float f) {
    u32 u;
    __builtin_memcpy(&u, &f, 4);
    u32 lsb = (u >> 16) & 1;
    u += 0x7fffu + lsb;   // round-to-nearest-even
    return (u16)(u >> 16);
}

// ---- Kernel 1 (tiny): pack rules -> 2 bits x 16 dims per u32 ----
__global__ __launch_bounds__(256) void k_pack(const int* __restrict__ rules,
                                              u32* __restrict__ packed) {
    int r = blockIdx.x * 256 + threadIdx.x;
    const int* q = rules + (size_t)r * ND;
    u32 pk = 0;
#pragma unroll
    for (int i = 0; i < 4; ++i) {
        intx4 v = *(const intx4*)(q + i * 4);
#pragma unroll
        for (int e = 0; e < 4; ++e) pk |= ((u32)(v[e] & 3)) << (2 * (i * 4 + e));
    }
    packed[r] = pk;
}

// ---- Kernel 2 (fused): blocks 0..255 = cons-reduce; blocks 256..1279 = per-b fs ----
__global__ __launch_bounds__(256) void k_mid(const float* __restrict__ cons,
                                             const float* __restrict__ x,
                                             const float* __restrict__ centers,
                                             const float* __restrict__ widths,
                                             const u32* __restrict__ packed,
                                             u16* __restrict__ s_consT,
                                             float* __restrict__ out_nfs,
                                             u16* __restrict__ fs_bf,
                                             float* __restrict__ out_xe,
                                             float* __restrict__ rowscale) {
    __shared__ u16 tile[16][68];
    __shared__ float xv[16];
    __shared__ float mftab[64];
    __shared__ float gtab[1024];
    __shared__ float wred[4];
    __shared__ float s_inv;
    int bid = blockIdx.x;
    int tid = threadIdx.x;
    if (bid < 256) {
        int rbase = bid * 16;
        int c = tid & 63;
        int rr = tid >> 6;
#pragma unroll
        for (int it = 0; it < 4; ++it, rr += 4) {
            const float* p = cons + (size_t)(rbase + rr) * (ND + 1) * NC + c;
            float s = 0.f;
#pragma unroll
            for (int j = 0; j < ND + 1; ++j) s += p[j * NC];
            tile[rr][c] = f2bf(s);
        }
        __syncthreads();
        int cc = tid >> 2;
        int r0 = (tid & 3) * 4;
        short4v v;
#pragma unroll
        for (int e = 0; e < 4; ++e) v[e] = (short)tile[r0 + e][cc];
        *(short4v*)(s_consT + (size_t)cc * NR + rbase + r0) = v;
        return;
    }
    int b = bid - 256;
    // hoisted independent loads: packed slice first (breaks load->use chains)
    uintx4 p[4];
#pragma unroll
    for (int it = 0; it < 4; ++it) p[it] = *(const uintx4*)(packed + it * 1024 + tid * 4);
    if (tid < 16) {
        float raw = x[b * 16 + tid];
        xv[tid] = raw;
        out_xe[b * 17 + tid] = raw;
    }
    if (tid == 16) out_xe[b * 17 + 16] = 1.0f;
    __syncthreads();
    if (tid < 64) {
        float diff = xv[tid >> 2] - centers[tid];
        float w = widths[tid];
        mftab[tid] = __expf(-diff * diff / (2.f * w * w)) + EPSF;
    }
    __syncthreads();
    for (int idx = tid; idx < 1024; idx += 256) {
        int g = idx >> 8, i = idx & 255;
        const float* mf = mftab + g * 16;
        gtab[idx] = mf[0 + (i & 3)] * mf[4 + ((i >> 2) & 3)] *
                    mf[8 + ((i >> 4) & 3)] * mf[12 + ((i >> 6) & 3)];
    }
    __syncthreads();
    floatx4 f[4];
    float lsum = 0.f;
#pragma unroll
    for (int it = 0; it < 4; ++it) {
#pragma unroll
        for (int e = 0; e < 4; ++e) {
            u32 pk = p[it][e];
            f[it][e] = gtab[pk & 255] * gtab[256 + ((pk >> 8) & 255)] *
                       gtab[512 + ((pk >> 16) & 255)] * gtab[768 + (pk >> 24)];
            lsum += f[it][e];
        }
    }
    for (int off = 32; off; off >>= 1) lsum += __shfl_down(lsum, off, 64);
    if ((tid & 63) == 0) wred[tid >> 6] = lsum;
    __syncthreads();
    if (tid == 0) s_inv = 1.f / (wred[0] + wred[1] + wred[2] + wred[3] + EPSF);
    __syncthreads();
    float inv = s_inv;
    if (tid == 0) {
        float s = 1.f;
        for (int i = 0; i < 16; ++i) s += xv[i];
        rowscale[b] = s * inv;
    }
    float* on = out_nfs + (size_t)b * NR;
    u16* ob = fs_bf + (size_t)b * NR;
#pragma unroll
    for (int it = 0; it < 4; ++it) {
        int r = it * 1024 + tid * 4;
        floatx4 v;
        short4v bv;
#pragma unroll
        for (int e = 0; e < 4; ++e) {
            v[e] = f[it][e] * inv;
            bv[e] = (short)f2bf(f[it][e]);
        }
        *(floatx4*)(on + r) = v;
        *(short4v*)(ob + r) = bv;
    }
}

// ---- Kernel 3: bf16 fs @ s_cons, KSPLIT=32; ALL 20 fragments prefetched to regs ----
__global__ __launch_bounds__(256) void k_gemm(const u16* __restrict__ fs_bf,
                                              const u16* __restrict__ s_consT,
                                              u16* __restrict__ part) {
    int rt = blockIdx.x;
    int ks = blockIdx.y;
    int tid = threadIdx.x;
    int wid = tid >> 6, lane = tid & 63;
    int arow = rt * 64 + wid * 16 + (lane & 15);
    int kbase = ks * (NR / KSPLIT) + (lane >> 4) * 8;
    const u16* aptr = fs_bf + (size_t)arow * NR + kbase;
    const u16* bptr = s_consT + (size_t)(lane & 15) * NR + kbase;
    // issue all 20 independent 16B loads before any compute (cold-latency paid once)
    short8 A[4], B[4][4];
#pragma unroll
    for (int t = 0; t < 4; ++t) A[t] = *(const short8*)(aptr + t * 32);
#pragma unroll
    for (int cb = 0; cb < 4; ++cb)
#pragma unroll
        for (int t = 0; t < 4; ++t)
            B[cb][t] = *(const short8*)(bptr + (size_t)cb * 16 * NR + t * 32);
    floatx4 acc[4] = {};
#pragma unroll
    for (int t = 0; t < 4; ++t)
#pragma unroll
        for (int cb = 0; cb < 4; ++cb)
            acc[cb] = __builtin_amdgcn_mfma_f32_16x16x32_bf16(A[t], B[cb][t], acc[cb], 0, 0, 0);
    u16* po = part + (size_t)ks * (NB * NC);
    int row0 = rt * 64 + wid * 16 + (lane >> 4) * 4;
#pragma unroll
    for (int cb = 0; cb < 4; ++cb)
#pragma unroll
        for (int reg = 0; reg < 4; ++reg)
            po[(size_t)(row0 + reg) * NC + cb * 16 + (lane & 15)] = f2bf(acc[cb][reg]);
}

// ---- Kernel 4: reduce K-splits, scale by rowscale = sx/den ----
__global__ __launch_bounds__(256) void k_out(const u16* __restrict__ part,
                                             const float* __restrict__ rowscale,
                                             float* __restrict__ out0) {
    int t = blockIdx.x * 256 + threadIdx.x;
    float a = 0.f;
#pragma unroll
    for (int ks = 0; ks < KSPLIT; ++ks) {
        u32 u = ((u32)part[(size_t)ks * (NB * NC) + t]) << 16;
        float v;
        __builtin_memcpy(&v, &u, 4);
        a += v;
    }
    out0[t] = a * rowscale[t >> 6];
}

extern "C" void kernel_launch(void* const* d_in, const int* in_sizes, int n_in,
                              void* d_out, int out_size, void* d_ws, size_t ws_size,
                              hipStream_t stream) {
    const float* x = (const float*)d_in[0];
    const float* centers = (const float*)d_in[1];
    const float* widths = (const float*)d_in[2];
    const float* cons = (const float*)d_in[3];
    const int* rules = (const int*)d_in[4];

    float* out = (float*)d_out;
    float* out_rule = out;                        // [1024,64]
    float* out_nfs = out + NB * NC;               // [1024,4096]
    float* out_xe = out + NB * NC + NB * NR;      // [1024,17]

    char* ws = (char*)d_ws;
    u16* s_consT = (u16*)ws;                                   // 512 KB
    u32* packed = (u32*)(ws + (512 << 10));                    // 16 KB
    float* rowscale = (float*)(ws + (512 << 10) + (16 << 10)); // 4 KB
    u16* fs_bf = (u16*)(ws + (512 << 10) + (24 << 10));        // 8 MB
    u16* part = (u16*)(ws + (512 << 10) + (24 << 10) + (size_t)NB * NR * 2);  // 4 MB

    k_pack<<<NR / 256, 256, 0, stream>>>(rules, packed);
    k_mid<<<256 + NB, 256, 0, stream>>>(cons, x, centers, widths, packed,
                                        s_consT, out_nfs, fs_bf, out_xe, rowscale);
    k_gemm<<<dim3(16, KSPLIT), 256, 0, stream>>>(fs_bf, s_consT, part);
    k_out<<<(NB * NC) / 256, 256, 0, stream>>>(part, rowscale, out_rule);
}

// Round 16
// 31.342 us; speedup vs baseline: 1.3908x; 1.0119x over previous
//
#include <hip/hip_runtime.h>
#include <hip/hip_bf16.h>

typedef __attribute__((ext_vector_type(8))) short short8;
typedef __attribute__((ext_vector_type(4))) short short4v;
typedef __attribute__((ext_vector_type(4))) float floatx4;
typedef __attribute__((ext_vector_type(4))) unsigned int uintx4;
typedef __attribute__((ext_vector_type(4))) int intx4;
typedef unsigned int u32;
typedef unsigned short u16;

#define NB 1024
#define ND 16
#define NM 4
#define NR 4096
#define NC 64
#define EPSF 1e-9f
#define KSPLIT 32

__device__ inline u16 f2bf(float f) {
    u32 u;
    __builtin_memcpy(&u, &f, 4);
    u32 lsb = (u >> 16) & 1;
    u += 0x7fffu + lsb;   // round-to-nearest-even
    return (u16)(u >> 16);
}

// ---- Node 1: cons-reduce -> s_consT (blocks 0..255); pack rules (256..271);
// ----         zero out_rule (272x256 = 69632 >= 65536 threads)
__global__ __launch_bounds__(256) void k_prep(const float* __restrict__ cons,
                                              const int* __restrict__ rules,
                                              u16* __restrict__ s_consT,
                                              u32* __restrict__ packed,
                                              float* __restrict__ out_rule) {
    __shared__ u16 tile[16][68];
    int bid = blockIdx.x;
    int tid = threadIdx.x;
    int gt = bid * 256 + tid;
    if (gt < NB * NC) out_rule[gt] = 0.f;   // zero for atomic epilogue
    if (bid >= 256) {
        int r = (bid - 256) * 256 + tid;
        const int* q = rules + (size_t)r * ND;
        u32 pk = 0;
#pragma unroll
        for (int i = 0; i < 4; ++i) {
            intx4 v = *(const intx4*)(q + i * 4);
#pragma unroll
            for (int e = 0; e < 4; ++e) pk |= ((u32)(v[e] & 3)) << (2 * (i * 4 + e));
        }
        packed[r] = pk;
        return;
    }
    int rbase = bid * 16;
    int c = tid & 63;
    int rr = tid >> 6;
#pragma unroll
    for (int it = 0; it < 4; ++it, rr += 4) {
        const float* p = cons + (size_t)(rbase + rr) * (ND + 1) * NC + c;
        float s = 0.f;
#pragma unroll
        for (int j = 0; j < ND + 1; ++j) s += p[j * NC];
        tile[rr][c] = f2bf(s);
    }
    __syncthreads();
    int cc = tid >> 2;
    int r0 = (tid & 3) * 4;
    short4v v;
#pragma unroll
    for (int e = 0; e < 4; ++e) v[e] = (short)tile[r0 + e][cc];
    *(short4v*)(s_consT + (size_t)cc * NR + rbase + r0) = v;
}

// ---- Node 2: per-b firing strengths; nfs fp32 + bf16 fs + rowscale ----
__global__ __launch_bounds__(256) void k_fs(const float* __restrict__ x,
                                            const float* __restrict__ centers,
                                            const float* __restrict__ widths,
                                            const u32* __restrict__ packed,
                                            float* __restrict__ out_nfs,
                                            u16* __restrict__ fs_bf,
                                            float* __restrict__ out_xe,
                                            float* __restrict__ rowscale) {
    __shared__ float xv[16];
    __shared__ float mftab[64];
    __shared__ float gtab[1024];
    __shared__ float wred[4];
    __shared__ float s_inv;
    int b = blockIdx.x;
    int tid = threadIdx.x;
    uintx4 p[4];
#pragma unroll
    for (int it = 0; it < 4; ++it) p[it] = *(const uintx4*)(packed + it * 1024 + tid * 4);
    if (tid < 16) {
        float raw = x[b * 16 + tid];
        xv[tid] = raw;
        out_xe[b * 17 + tid] = raw;
    }
    if (tid == 16) out_xe[b * 17 + 16] = 1.0f;
    __syncthreads();
    if (tid < 64) {
        float diff = xv[tid >> 2] - centers[tid];
        float w = widths[tid];
        mftab[tid] = __expf(-diff * diff / (2.f * w * w)) + EPSF;
    }
    __syncthreads();
    for (int idx = tid; idx < 1024; idx += 256) {
        int g = idx >> 8, i = idx & 255;
        const float* mf = mftab + g * 16;
        gtab[idx] = mf[0 + (i & 3)] * mf[4 + ((i >> 2) & 3)] *
                    mf[8 + ((i >> 4) & 3)] * mf[12 + ((i >> 6) & 3)];
    }
    __syncthreads();
    floatx4 f[4];
    float lsum = 0.f;
#pragma unroll
    for (int it = 0; it < 4; ++it) {
#pragma unroll
        for (int e = 0; e < 4; ++e) {
            u32 pk = p[it][e];
            f[it][e] = gtab[pk & 255] * gtab[256 + ((pk >> 8) & 255)] *
                       gtab[512 + ((pk >> 16) & 255)] * gtab[768 + (pk >> 24)];
            lsum += f[it][e];
        }
    }
    for (int off = 32; off; off >>= 1) lsum += __shfl_down(lsum, off, 64);
    if ((tid & 63) == 0) wred[tid >> 6] = lsum;
    __syncthreads();
    if (tid == 0) s_inv = 1.f / (wred[0] + wred[1] + wred[2] + wred[3] + EPSF);
    __syncthreads();
    float inv = s_inv;
    if (tid == 0) {
        float s = 1.f;
        for (int i = 0; i < 16; ++i) s += xv[i];
        rowscale[b] = s * inv;   // (1+sum x)/den, folded into gemm epilogue
    }
    float* on = out_nfs + (size_t)b * NR;
    u16* ob = fs_bf + (size_t)b * NR;
#pragma unroll
    for (int it = 0; it < 4; ++it) {
        int r = it * 1024 + tid * 4;
        floatx4 v;
        short4v bv;
#pragma unroll
        for (int e = 0; e < 4; ++e) {
            v[e] = f[it][e] * inv;            // fp32 normalized nfs (output 1)
            bv[e] = (short)f2bf(f[it][e]);    // bf16 unnormalized fs (GEMM A)
        }
        *(floatx4*)(on + r) = v;
        *(short4v*)(ob + r) = bv;
    }
}

// ---- Node 3: bf16 fs @ s_cons, prefetch-all, epilogue = pre-scaled atomicAdd ----
__global__ __launch_bounds__(256) void k_gemm(const u16* __restrict__ fs_bf,
                                              const u16* __restrict__ s_consT,
                                              const float* __restrict__ rowscale,
                                              float* __restrict__ out_rule) {
    int rt = blockIdx.x;
    int ks = blockIdx.y;
    int tid = threadIdx.x;
    int wid = tid >> 6, lane = tid & 63;
    int arow = rt * 64 + wid * 16 + (lane & 15);
    int kbase = ks * (NR / KSPLIT) + (lane >> 4) * 8;
    const u16* aptr = fs_bf + (size_t)arow * NR + kbase;
    const u16* bptr = s_consT + (size_t)(lane & 15) * NR + kbase;
    short8 A[4], B[4][4];
#pragma unroll
    for (int t = 0; t < 4; ++t) A[t] = *(const short8*)(aptr + t * 32);
#pragma unroll
    for (int cb = 0; cb < 4; ++cb)
#pragma unroll
        for (int t = 0; t < 4; ++t)
            B[cb][t] = *(const short8*)(bptr + (size_t)cb * 16 * NR + t * 32);
    floatx4 acc[4] = {};
#pragma unroll
    for (int t = 0; t < 4; ++t)
#pragma unroll
        for (int cb = 0; cb < 4; ++cb)
            acc[cb] = __builtin_amdgcn_mfma_f32_16x16x32_bf16(A[t], B[cb][t], acc[cb], 0, 0, 0);
    int row0 = rt * 64 + wid * 16 + (lane >> 4) * 4;
    float s4[4];
#pragma unroll
    for (int reg = 0; reg < 4; ++reg) s4[reg] = rowscale[row0 + reg];
#pragma unroll
    for (int cb = 0; cb < 4; ++cb)
#pragma unroll
        for (int reg = 0; reg < 4; ++reg)
            atomicAdd(out_rule + (size_t)(row0 + reg) * NC + cb * 16 + (lane & 15),
                      acc[cb][reg] * s4[reg]);
}

extern "C" void kernel_launch(void* const* d_in, const int* in_sizes, int n_in,
                              void* d_out, int out_size, void* d_ws, size_t ws_size,
                              hipStream_t stream) {
    const float* x = (const float*)d_in[0];
    const float* centers = (const float*)d_in[1];
    const float* widths = (const float*)d_in[2];
    const float* cons = (const float*)d_in[3];
    const int* rules = (const int*)d_in[4];

    float* out = (float*)d_out;
    float* out_rule = out;                        // [1024,64]
    float* out_nfs = out + NB * NC;               // [1024,4096]
    float* out_xe = out + NB * NC + NB * NR;      // [1024,17]

    char* ws = (char*)d_ws;
    u16* s_consT = (u16*)ws;                                   // 512 KB
    u32* packed = (u32*)(ws + (512 << 10));                    // 16 KB
    float* rowscale = (float*)(ws + (512 << 10) + (16 << 10)); // 4 KB
    u16* fs_bf = (u16*)(ws + (512 << 10) + (24 << 10));        // 8 MB

    k_prep<<<272, 256, 0, stream>>>(cons, rules, s_consT, packed, out_rule);
    k_fs<<<NB, 256, 0, stream>>>(x, centers, widths, packed, out_nfs, fs_bf,
                                 out_xe, rowscale);
    k_gemm<<<dim3(16, KSPLIT), 256, 0, stream>>>(fs_bf, s_consT, rowscale, out_rule);
}